// Round 5
// baseline (394.805 us; speedup 1.0000x reference)
//
#include <hip/hip_runtime.h>
#include <hip/hip_bf16.h>

#define HALF_ROWS 262144
#define TAU 0.04f
#define BT_OFF 1024
#define LIST_OFF (BT_OFF + 320 * 512 * 2)   // 1024 + 327680

typedef __attribute__((ext_vector_type(8))) short s16x8;
typedef __attribute__((ext_vector_type(4))) unsigned short u16x4;
typedef __attribute__((ext_vector_type(4))) float f32x4;

__device__ __forceinline__ unsigned short f2bf(float f) {
  union { float f; unsigned u; } v; v.f = f;
  unsigned r = v.u + 0x7fffu + ((v.u >> 16) & 1u);   // RTNE
  return (unsigned short)(r >> 16);
}

// ---- prep: W1 -> Bf in MFMA-fragment order, zero counter ---------------------
__global__ void moe_prep(const float* __restrict__ gw1, const float* __restrict__ aw1,
                         const float* __restrict__ bw1, unsigned short* __restrict__ Bf,
                         unsigned* __restrict__ cnt) {
  if (blockIdx.x == 0 && threadIdx.x == 0) *cnt = 0u;
  int idx = blockIdx.x * 512 + threadIdx.x;          // 320*512 = 163840
  int j = idx & 7, l = (idx >> 3) & 63, ks = (idx >> 9) & 15, cb = idx >> 13;
  int col = cb * 16 + (l & 15);
  int k = ks * 32 + ((l >> 4) << 3) + j;
  float v;
  if (col < 64)       v = gw1[k * 64 + col];
  else if (col < 192) v = aw1[k * 128 + (col - 64)];
  else                v = bw1[k * 128 + (col - 192)];
  Bf[idx] = f2bf(v);
}

// ---- main: 1 block = 8 consecutive 64-row panels, pipelined ------------------
// issue(p+1) -> compute(p) -> epilogue(p) -> commit(p+1); loads in flight
// across the whole compute phase => continuous HBM streaming.
__global__ __launch_bounds__(512, 2) void moe_main(
    const float* __restrict__ x, const unsigned short* __restrict__ Bf,
    const float* __restrict__ gb1, const float* __restrict__ gw2, const float* __restrict__ gb2,
    const float* __restrict__ ab1, const float* __restrict__ aw2, const float* __restrict__ ab2,
    const float* __restrict__ bb1, const float* __restrict__ bw2, const float* __restrict__ bb2,
    float* __restrict__ out, unsigned* __restrict__ cnt, unsigned* __restrict__ list, int cap) {
  __shared__ unsigned short A[64 * 512];             // 64KB, XOR-swizzled
  __shared__ float part[64 * 4 * 6];                 // 6KB partials

  const int tid = threadIdx.x;
  const int w = tid >> 6, l = tid & 63;
  const int wr = w >> 2, wc = w & 3;                 // 2 row x 4 col wave groups
  const int lo = l & 15, hi = l >> 4;
  const int p0 = blockIdx.x * 8;                     // 512 blocks x 8 panels x 64 rows

  // epilogue constants (uniform per panel)
  float b1v[5], w0v[5], w1v[5];
  int head[5];
#pragma unroll
  for (int ct = 0; ct < 5; ++ct) {
    int c0 = wc * 80 + ct * 16;
    int col = c0 + lo;
    int hd = c0 < 64 ? 0 : (c0 < 192 ? 1 : 2);
    head[ct] = hd;
    if (hd == 0)      { b1v[ct] = gb1[col];           w0v[ct] = gw2[col * 2];       w1v[ct] = gw2[col * 2 + 1]; }
    else if (hd == 1) { int c = col - 64;  b1v[ct] = ab1[c]; w0v[ct] = aw2[c * 2]; w1v[ct] = aw2[c * 2 + 1]; }
    else              { int c = col - 192; b1v[ct] = bb1[c]; w0v[ct] = bw2[c * 2]; w1v[ct] = bw2[c * 2 + 1]; }
  }

  f32x4 st[16];                                      // next panel, in flight
  auto issueP = [&](int panel) {
    long br = (long)panel * 64;
#pragma unroll
    for (int u = 0; u < 16; ++u) {
      int i = tid + u * 512;
      int row = i >> 7, kq = i & 127;
      long roff = br + row + ((kq >> 6) ? (long)HALF_ROWS : 0L);
      st[u] = *(const f32x4*)(x + roff * 256 + (kq & 63) * 4);
    }
  };
  auto commitP = [&]() {
#pragma unroll
    for (int u = 0; u < 16; ++u) {
      int i = tid + u * 512;
      int row = i >> 7, kq = i & 127;
      u16x4 p4;
      p4[0] = f2bf(st[u][0]); p4[1] = f2bf(st[u][1]);
      p4[2] = f2bf(st[u][2]); p4[3] = f2bf(st[u][3]);
      int byte = (row * 1024 + kq * 8) ^ ((row & 7) << 4);
      *(u16x4*)((char*)A + byte) = p4;
    }
  };

  issueP(p0);
  commitP();
  __syncthreads();

#pragma unroll 1
  for (int pp = 0; pp < 8; ++pp) {
    const int panel = p0 + pp;
    const long br = (long)panel * 64;
    const bool hasNext = pp < 7;
    if (hasNext) issueP(panel + 1);                  // in flight through compute

    f32x4 acc[2][5];
#pragma unroll
    for (int i = 0; i < 2; i++)
#pragma unroll
      for (int j = 0; j < 5; j++) acc[i][j] = (f32x4){0.f, 0.f, 0.f, 0.f};

#pragma unroll 4
    for (int ks = 0; ks < 16; ++ks) {
      s16x8 bfr[5], afr[2];
#pragma unroll
      for (int ct = 0; ct < 5; ++ct)
        bfr[ct] = *(const s16x8*)(Bf + (((size_t)((wc * 5 + ct) * 16 + ks)) << 9) + l * 8);
#pragma unroll
      for (int rt = 0; rt < 2; ++rt) {
        int row = wr * 32 + rt * 16 + lo;
        int byte = (row * 1024 + ks * 64 + hi * 16) ^ ((l & 7) << 4);  // row&7==l&7
        afr[rt] = *(const s16x8*)((const char*)A + byte);
      }
#pragma unroll
      for (int rt = 0; rt < 2; ++rt)
#pragma unroll
        for (int ct = 0; ct < 5; ++ct)
          acc[rt][ct] = __builtin_amdgcn_mfma_f32_16x16x32_bf16(
              afr[rt], bfr[ct], acc[rt][ct], 0, 0, 0);
    }

    // epilogue partials -> part (separate LDS; A still intact for stragglers)
#pragma unroll
    for (int rt = 0; rt < 2; ++rt) {
      float pg0[4] = {0,0,0,0}, pg1[4] = {0,0,0,0};
      float pa0[4] = {0,0,0,0}, pa1[4] = {0,0,0,0};
      float pq0[4] = {0,0,0,0}, pq1[4] = {0,0,0,0};
#pragma unroll
      for (int ct = 0; ct < 5; ++ct)
#pragma unroll
        for (int j = 0; j < 4; ++j) {
          float h = fmaxf(acc[rt][ct][j] + b1v[ct], 0.f);
          float t0 = h * w0v[ct], t1 = h * w1v[ct];
          if (head[ct] == 0)      { pg0[j] += t0; pg1[j] += t1; }
          else if (head[ct] == 1) { pa0[j] += t0; pa1[j] += t1; }
          else                    { pq0[j] += t0; pq1[j] += t1; }
        }
#pragma unroll
      for (int m = 1; m < 16; m <<= 1)
#pragma unroll
        for (int j = 0; j < 4; ++j) {
          pg0[j] += __shfl_xor(pg0[j], m); pg1[j] += __shfl_xor(pg1[j], m);
          pa0[j] += __shfl_xor(pa0[j], m); pa1[j] += __shfl_xor(pa1[j], m);
          pq0[j] += __shfl_xor(pq0[j], m); pq1[j] += __shfl_xor(pq1[j], m);
        }
      if (lo == 0) {
#pragma unroll
        for (int j = 0; j < 4; ++j) {
          int r = wr * 32 + rt * 16 + hi * 4 + j;
          float* pp2 = part + (r * 4 + wc) * 6;
          pp2[0] = pg0[j]; pp2[1] = pg1[j]; pp2[2] = pa0[j];
          pp2[3] = pa1[j]; pp2[4] = pq0[j]; pp2[5] = pq1[j];
        }
      }
    }
    __syncthreads();                                 // part ready; A reads done

    if (tid < 64) {
      float g0 = 0, g1 = 0, a0 = 0, a1 = 0, e0 = 0, e1 = 0;
#pragma unroll
      for (int k2 = 0; k2 < 4; k2++) {
        float* pp2 = part + (tid * 4 + k2) * 6;
        g0 += pp2[0]; g1 += pp2[1]; a0 += pp2[2]; a1 += pp2[3]; e0 += pp2[4]; e1 += pp2[5];
      }
      float gl0 = g0 + gb2[0], gl1 = g1 + gb2[1];
      float fa0 = a0 + ab2[0], fa1 = a1 + ab2[1];
      float fb0 = e0 + bb2[0], fb1 = e1 + bb2[1];
      bool m0 = gl0 >= gl1;
      long grow = br + tid;
      f32x4 o;
      o[0] = m0 ? fa0 : 0.f; o[1] = m0 ? fa1 : 0.f;
      o[2] = m0 ? 0.f : fb0; o[3] = m0 ? 0.f : fb1;
      *(f32x4*)(out + grow * 4) = o;
      float diff = gl0 - gl1;
      if (fabsf(diff) < TAU && cap > 0) {
        unsigned u = atomicAdd(cnt, 1u);
        if (u < (unsigned)cap) {
          unsigned* e = list + (size_t)u * 8;
          e[0] = (unsigned)grow;
          float* ef = (float*)(e + 4);
          ef[0] = fa0; ef[1] = fa1; ef[2] = fb0; ef[3] = fb1;
        }
      }
    }
    if (hasNext) commitP();                          // writes A; part reads done via barrier
    __syncthreads();
  }
}

// ---- fixup: fp64 gate recompute for borderline rows --------------------------
__global__ void moe_fixup(const float* __restrict__ x,
                          const float* __restrict__ gw1, const float* __restrict__ gb1,
                          const float* __restrict__ gw2, const float* __restrict__ gb2,
                          float* __restrict__ out, const unsigned* __restrict__ cnt,
                          const unsigned* __restrict__ list, int cap) {
  unsigned n = *cnt;
  if (n > (unsigned)cap) n = (unsigned)cap;
  const int l = threadIdx.x & 63;
  const int wid = blockIdx.x * (blockDim.x >> 6) + (threadIdx.x >> 6);
  const int nw = gridDim.x * (blockDim.x >> 6);
  for (unsigned e = wid; e < n; e += nw) {
    const unsigned* ent = list + (size_t)e * 8;
    unsigned row = ent[0];
    const float* ef = (const float*)(ent + 4);
    const float* xr0 = x + (long)row * 256;
    const float* xr1 = x + ((long)row + HALF_ROWS) * 256;
    double a0 = 0.0, a1 = 0.0, a2 = 0.0, a3 = 0.0;
#pragma unroll 4
    for (int d = 0; d < 256; d += 4) {
      a0 += (double)xr0[d]     * (double)gw1[d * 64 + l];
      a1 += (double)xr0[d + 1] * (double)gw1[(d + 1) * 64 + l];
      a2 += (double)xr0[d + 2] * (double)gw1[(d + 2) * 64 + l];
      a3 += (double)xr0[d + 3] * (double)gw1[(d + 3) * 64 + l];
    }
#pragma unroll 4
    for (int d = 0; d < 256; d += 4) {
      a0 += (double)xr1[d]     * (double)gw1[(d + 256) * 64 + l];
      a1 += (double)xr1[d + 1] * (double)gw1[(d + 257) * 64 + l];
      a2 += (double)xr1[d + 2] * (double)gw1[(d + 258) * 64 + l];
      a3 += (double)xr1[d + 3] * (double)gw1[(d + 259) * 64 + l];
    }
    double h = a0 + a1 + a2 + a3 + (double)gb1[l];
    h = h > 0.0 ? h : 0.0;
    double t0 = h * (double)gw2[l * 2];
    double t1 = h * (double)gw2[l * 2 + 1];
#pragma unroll
    for (int m = 1; m < 64; m <<= 1) {
      t0 += __shfl_xor(t0, m);
      t1 += __shfl_xor(t1, m);
    }
    if (l == 0) {
      bool m0 = (t0 + (double)gb2[0]) >= (t1 + (double)gb2[1]);
      f32x4 o;
      o[0] = m0 ? ef[0] : 0.f; o[1] = m0 ? ef[1] : 0.f;
      o[2] = m0 ? 0.f : ef[2]; o[3] = m0 ? 0.f : ef[3];
      *(f32x4*)(out + (size_t)row * 4) = o;
    }
  }
}

extern "C" void kernel_launch(void* const* d_in, const int* in_sizes, int n_in,
                              void* d_out, int out_size, void* d_ws, size_t ws_size,
                              hipStream_t stream) {
  const float* x   = (const float*)d_in[0];
  const float* gw1 = (const float*)d_in[1];
  const float* gb1 = (const float*)d_in[2];
  const float* gw2 = (const float*)d_in[3];
  const float* gb2 = (const float*)d_in[4];
  const float* aw1 = (const float*)d_in[5];
  const float* ab1 = (const float*)d_in[6];
  const float* aw2 = (const float*)d_in[7];
  const float* ab2 = (const float*)d_in[8];
  const float* bw1 = (const float*)d_in[9];
  const float* bb1 = (const float*)d_in[10];
  const float* bw2 = (const float*)d_in[11];
  const float* bb2 = (const float*)d_in[12];
  float* out = (float*)d_out;

  unsigned char* ws = (unsigned char*)d_ws;
  unsigned* cnt = (unsigned*)ws;
  unsigned short* Bf = (unsigned short*)(ws + BT_OFF);
  unsigned* list = (unsigned*)(ws + LIST_OFF);
  long cap_l = ((long)ws_size - (long)LIST_OFF) / 32;
  int cap = cap_l < 0 ? 0 : (cap_l > 262144 ? 262144 : (int)cap_l);

  moe_prep<<<320, 512, 0, stream>>>(gw1, aw1, bw1, Bf, cnt);
  moe_main<<<512, 512, 0, stream>>>(x, Bf, gb1, gw2, gb2, ab1, aw2, ab2,
                                    bb1, bw2, bb2, out, cnt, list, cap);
  moe_fixup<<<1024, 256, 0, stream>>>(x, gw1, gb1, gw2, gb2, out, cnt, list, cap);
}

// Round 7
// 307.165 us; speedup vs baseline: 1.2853x; 1.2853x over previous
//
#include <hip/hip_runtime.h>
#include <hip/hip_bf16.h>

#define HALF_ROWS 262144
#define TAU 0.04f
#define BT_OFF 1024
#define LIST_OFF (BT_OFF + 320 * 512 * 2)   // 1024 + 327680

typedef __attribute__((ext_vector_type(8))) short s16x8;
typedef __attribute__((ext_vector_type(8))) unsigned short u16x8;
typedef __attribute__((ext_vector_type(4))) float f32x4;

__device__ __forceinline__ unsigned short f2bf(float f) {
  union { float f; unsigned u; } v; v.f = f;
  unsigned r = v.u + 0x7fffu + ((v.u >> 16) & 1u);   // RTNE
  return (unsigned short)(r >> 16);
}

#define GLOAD_LDS16(g, p) \
  __builtin_amdgcn_global_load_lds((const __attribute__((address_space(1))) void*)(g), \
                                   (__attribute__((address_space(3))) void*)(p), 16, 0, 0)

// ---- prep: W1 -> Bf in MFMA-fragment order [cb20][ksg16][lane64][8] ----------
// entry (cb,ksg,l) holds col = cb*16+(l&15), k = ksg*32+(l>>4)*8 + j
__global__ void moe_prep(const float* __restrict__ gw1, const float* __restrict__ aw1,
                         const float* __restrict__ bw1, unsigned short* __restrict__ Bf,
                         unsigned* __restrict__ cnt) {
  if (blockIdx.x == 0 && threadIdx.x == 0) *cnt = 0u;
  int idx = blockIdx.x * 512 + threadIdx.x;          // 320*512 = 163840
  int j = idx & 7, l = (idx >> 3) & 63, ks = (idx >> 9) & 15, cb = idx >> 13;
  int col = cb * 16 + (l & 15);
  int k = ks * 32 + ((l >> 4) << 3) + j;
  float v;
  if (col < 64)       v = gw1[k * 64 + col];
  else if (col < 192) v = aw1[k * 128 + (col - 64)];
  else                v = bw1[k * 128 + (col - 192)];
  Bf[idx] = f2bf(v);
}

// ---- main: 64 rows x 320 cols per block; BK=64; A+B in LDS, fragment order ---
// B staged by global_load_lds (bf16->bf16, no regs); A(kc+1) loads stay in
// flight across s_barrier via counted vmcnt(2).
__global__ __launch_bounds__(512, 4) void moe_main(
    const float* __restrict__ x, const unsigned short* __restrict__ Bf,
    const float* __restrict__ gb1, const float* __restrict__ gw2, const float* __restrict__ gb2,
    const float* __restrict__ ab1, const float* __restrict__ aw2, const float* __restrict__ ab2,
    const float* __restrict__ bb1, const float* __restrict__ bw2, const float* __restrict__ bb2,
    float* __restrict__ out, unsigned* __restrict__ cnt, unsigned* __restrict__ list, int cap) {
  __shared__ char L[49152];                 // 8KB A + 40KB B; part aliases A
  char* ALb = L;                            // [g4][ks2][l64][16B] = 512 entries
  char* BLb = L + 8192;                     // [seg40][l64][16B]  = 2560 entries
  float* part = (float*)L;                  // 6KB, used after last compute

  const int tid = threadIdx.x;
  const int bid = blockIdx.x;
  const int w = tid >> 6, l = tid & 63;
  const int wr = w >> 2, wc = w & 3;        // 2 row-groups x 4 col-groups
  const int lo = l & 15, hi = l >> 4;
  const long br = (long)bid * 64;

  // A staging: thread == entry: g=tid>>7, ks=(tid>>6)&1, lane=tid&63
  const int arow = ((tid >> 7) << 4) + (tid & 15);          // 0..63
  const int akl  = ((tid >> 6) & 1) * 32 + ((tid >> 4) & 3) * 8;

  f32x4 sa0, sa1;                                           // 8 floats in flight
  auto issueA = [&](int kc) {
    const float* p = x + ((long)(kc >= 4 ? HALF_ROWS : 0) + br + arow) * 256
                       + (kc & 3) * 64 + akl;
    sa0 = *(const f32x4*)p;
    sa1 = *(const f32x4*)(p + 4);
  };
  auto commitA = [&]() {
    u16x8 u;
    const float* s0 = (const float*)&sa0;
    const float* s1 = (const float*)&sa1;
#pragma unroll
    for (int i = 0; i < 4; ++i) { u[i] = f2bf(s0[i]); u[4 + i] = f2bf(s1[i]); }
    *(u16x8*)(ALb + (size_t)tid * 16) = u;
  };

  f32x4 acc[2][5];
#pragma unroll
  for (int i = 0; i < 2; i++)
#pragma unroll
    for (int j = 0; j < 5; j++) acc[i][j] = (f32x4){0.f, 0.f, 0.f, 0.f};

  issueA(0);

#pragma unroll 1
  for (int kc = 0; kc < 8; ++kc) {
    // B DMA: 5 segments/wave, each 1KB contiguous LDS (wave-uniform base + l*16)
#pragma unroll
    for (int s5 = 0; s5 < 5; ++s5) {
      int s = w * 5 + s5;                   // 0..39: ct = s>>1, ks = s&1
      const unsigned short* g = Bf + ((size_t)(((s >> 1) * 16 + kc * 2 + (s & 1)) * 64 + l)) * 8;
      GLOAD_LDS16(g, BLb + (size_t)s * 1024);
    }
    asm volatile("" ::: "memory");          // pin: gloads above, A-prefetch below
    commitA();                              // waits sa only (vmcnt(5)), ds_write A
    if (kc < 7) {
      issueA(kc + 1);                       // 2 loads, stay in flight
      asm volatile("s_waitcnt vmcnt(2) lgkmcnt(0)" ::: "memory");
    } else {
      asm volatile("s_waitcnt vmcnt(0) lgkmcnt(0)" ::: "memory");
    }
    __builtin_amdgcn_s_barrier();

    // compute: 2 ks-steps x (2 A-frags + 5 B-frags + 10 MFMA)
#pragma unroll
    for (int ks = 0; ks < 2; ++ks) {
      s16x8 afr[2], bfr[5];
#pragma unroll
      for (int rt = 0; rt < 2; ++rt)
        afr[rt] = *(const s16x8*)(ALb + (size_t)((((wr * 2 + rt) * 2 + ks) * 64 + l)) * 16);
#pragma unroll
      for (int ct = 0; ct < 5; ++ct)
        bfr[ct] = *(const s16x8*)(BLb + (size_t)((((wc * 5 + ct) * 2 + ks) * 64 + l)) * 16);
#pragma unroll
      for (int rt = 0; rt < 2; ++rt)
#pragma unroll
        for (int ct = 0; ct < 5; ++ct)
          acc[rt][ct] = __builtin_amdgcn_mfma_f32_16x16x32_bf16(
              afr[rt], bfr[ct], acc[rt][ct], 0, 0, 0);
    }
    asm volatile("" ::: "memory");
    __builtin_amdgcn_s_barrier();           // all reads retired before next stage
  }

  // ---- epilogue: bias+relu+3 tiny heads; head uniform per (wc,ct) tile --------
  float b1v[5], w0v[5], w1v[5];
  int head[5];
#pragma unroll
  for (int ct = 0; ct < 5; ++ct) {
    int c0 = (wc * 5 + ct) * 16;
    int col = c0 + lo;
    int hd = c0 < 64 ? 0 : (c0 < 192 ? 1 : 2);
    head[ct] = hd;
    if (hd == 0)      { b1v[ct] = gb1[col];           w0v[ct] = gw2[col * 2];       w1v[ct] = gw2[col * 2 + 1]; }
    else if (hd == 1) { int c = col - 64;  b1v[ct] = ab1[c]; w0v[ct] = aw2[c * 2]; w1v[ct] = aw2[c * 2 + 1]; }
    else              { int c = col - 192; b1v[ct] = bb1[c]; w0v[ct] = bw2[c * 2]; w1v[ct] = bw2[c * 2 + 1]; }
  }
#pragma unroll
  for (int rt = 0; rt < 2; ++rt) {
    float pg0[4] = {0,0,0,0}, pg1[4] = {0,0,0,0};
    float pa0[4] = {0,0,0,0}, pa1[4] = {0,0,0,0};
    float pq0[4] = {0,0,0,0}, pq1[4] = {0,0,0,0};
#pragma unroll
    for (int ct = 0; ct < 5; ++ct)
#pragma unroll
      for (int j = 0; j < 4; ++j) {
        float h = fmaxf(acc[rt][ct][j] + b1v[ct], 0.f);
        float t0 = h * w0v[ct], t1 = h * w1v[ct];
        if (head[ct] == 0)      { pg0[j] += t0; pg1[j] += t1; }
        else if (head[ct] == 1) { pa0[j] += t0; pa1[j] += t1; }
        else                    { pq0[j] += t0; pq1[j] += t1; }
      }
#pragma unroll
    for (int m = 1; m < 16; m <<= 1)
#pragma unroll
      for (int j = 0; j < 4; ++j) {
        pg0[j] += __shfl_xor(pg0[j], m); pg1[j] += __shfl_xor(pg1[j], m);
        pa0[j] += __shfl_xor(pa0[j], m); pa1[j] += __shfl_xor(pa1[j], m);
        pq0[j] += __shfl_xor(pq0[j], m); pq1[j] += __shfl_xor(pq1[j], m);
      }
    if (lo == 0) {
#pragma unroll
      for (int j = 0; j < 4; ++j) {
        int r = wr * 32 + rt * 16 + hi * 4 + j;        // 0..63
        float* pp = part + (r * 4 + wc) * 6;
        pp[0] = pg0[j]; pp[1] = pg1[j]; pp[2] = pa0[j];
        pp[3] = pa1[j]; pp[4] = pq0[j]; pp[5] = pq1[j];
      }
    }
  }
  __syncthreads();

  if (tid < 64) {
    float g0 = 0, g1 = 0, a0 = 0, a1 = 0, e0 = 0, e1 = 0;
#pragma unroll
    for (int k2 = 0; k2 < 4; k2++) {
      float* pp = part + (tid * 4 + k2) * 6;
      g0 += pp[0]; g1 += pp[1]; a0 += pp[2]; a1 += pp[3]; e0 += pp[4]; e1 += pp[5];
    }
    float gl0 = g0 + gb2[0], gl1 = g1 + gb2[1];
    float fa0 = a0 + ab2[0], fa1 = a1 + ab2[1];
    float fb0 = e0 + bb2[0], fb1 = e1 + bb2[1];
    bool m0 = gl0 >= gl1;
    long grow = br + tid;
    f32x4 o;
    o[0] = m0 ? fa0 : 0.f; o[1] = m0 ? fa1 : 0.f;
    o[2] = m0 ? 0.f : fb0; o[3] = m0 ? 0.f : fb1;
    *(f32x4*)(out + grow * 4) = o;
    float diff = gl0 - gl1;
    if (fabsf(diff) < TAU && cap > 0) {
      unsigned u = atomicAdd(cnt, 1u);
      if (u < (unsigned)cap) {
        unsigned* e = list + (size_t)u * 8;
        e[0] = (unsigned)grow;
        float* ef = (float*)(e + 4);
        ef[0] = fa0; ef[1] = fa1; ef[2] = fb0; ef[3] = fb1;
      }
    }
  }
}

// ---- fixup: fp64 gate recompute for borderline rows --------------------------
__global__ void moe_fixup(const float* __restrict__ x,
                          const float* __restrict__ gw1, const float* __restrict__ gb1,
                          const float* __restrict__ gw2, const float* __restrict__ gb2,
                          float* __restrict__ out, const unsigned* __restrict__ cnt,
                          const unsigned* __restrict__ list, int cap) {
  unsigned n = *cnt;
  if (n > (unsigned)cap) n = (unsigned)cap;
  const int l = threadIdx.x & 63;
  const int wid = blockIdx.x * (blockDim.x >> 6) + (threadIdx.x >> 6);
  const int nw = gridDim.x * (blockDim.x >> 6);
  for (unsigned e = wid; e < n; e += nw) {
    const unsigned* ent = list + (size_t)e * 8;
    unsigned row = ent[0];
    const float* ef = (const float*)(ent + 4);
    const float* xr0 = x + (long)row * 256;
    const float* xr1 = x + ((long)row + HALF_ROWS) * 256;
    double a0 = 0.0, a1 = 0.0, a2 = 0.0, a3 = 0.0;
#pragma unroll 4
    for (int d = 0; d < 256; d += 4) {
      a0 += (double)xr0[d]     * (double)gw1[d * 64 + l];
      a1 += (double)xr0[d + 1] * (double)gw1[(d + 1) * 64 + l];
      a2 += (double)xr0[d + 2] * (double)gw1[(d + 2) * 64 + l];
      a3 += (double)xr0[d + 3] * (double)gw1[(d + 3) * 64 + l];
    }
#pragma unroll 4
    for (int d = 0; d < 256; d += 4) {
      a0 += (double)xr1[d]     * (double)gw1[(d + 256) * 64 + l];
      a1 += (double)xr1[d + 1] * (double)gw1[(d + 257) * 64 + l];
      a2 += (double)xr1[d + 2] * (double)gw1[(d + 258) * 64 + l];
      a3 += (double)xr1[d + 3] * (double)gw1[(d + 259) * 64 + l];
    }
    double h = a0 + a1 + a2 + a3 + (double)gb1[l];
    h = h > 0.0 ? h : 0.0;
    double t0 = h * (double)gw2[l * 2];
    double t1 = h * (double)gw2[l * 2 + 1];
#pragma unroll
    for (int m = 1; m < 64; m <<= 1) {
      t0 += __shfl_xor(t0, m);
      t1 += __shfl_xor(t1, m);
    }
    if (l == 0) {
      bool m0 = (t0 + (double)gb2[0]) >= (t1 + (double)gb2[1]);
      f32x4 o;
      o[0] = m0 ? ef[0] : 0.f; o[1] = m0 ? ef[1] : 0.f;
      o[2] = m0 ? 0.f : ef[2]; o[3] = m0 ? 0.f : ef[3];
      *(f32x4*)(out + (size_t)row * 4) = o;
    }
  }
}

extern "C" void kernel_launch(void* const* d_in, const int* in_sizes, int n_in,
                              void* d_out, int out_size, void* d_ws, size_t ws_size,
                              hipStream_t stream) {
  const float* x   = (const float*)d_in[0];
  const float* gw1 = (const float*)d_in[1];
  const float* gb1 = (const float*)d_in[2];
  const float* gw2 = (const float*)d_in[3];
  const float* gb2 = (const float*)d_in[4];
  const float* aw1 = (const float*)d_in[5];
  const float* ab1 = (const float*)d_in[6];
  const float* aw2 = (const float*)d_in[7];
  const float* ab2 = (const float*)d_in[8];
  const float* bw1 = (const float*)d_in[9];
  const float* bb1 = (const float*)d_in[10];
  const float* bw2 = (const float*)d_in[11];
  const float* bb2 = (const float*)d_in[12];
  float* out = (float*)d_out;

  unsigned char* ws = (unsigned char*)d_ws;
  unsigned* cnt = (unsigned*)ws;
  unsigned short* Bf = (unsigned short*)(ws + BT_OFF);
  unsigned* list = (unsigned*)(ws + LIST_OFF);
  long cap_l = ((long)ws_size - (long)LIST_OFF) / 32;
  int cap = cap_l < 0 ? 0 : (cap_l > 262144 ? 262144 : (int)cap_l);

  moe_prep<<<320, 512, 0, stream>>>(gw1, aw1, bw1, Bf, cnt);
  moe_main<<<4096, 512, 0, stream>>>(x, Bf, gb1, gw2, gb2, ab1, aw2, ab2,
                                     bb1, bw2, bb2, out, cnt, list, cap);
  moe_fixup<<<1024, 256, 0, stream>>>(x, gw1, gb1, gw2, gb2, out, cnt, list, cap);
}